// Round 5
// baseline (44.171 us; speedup 1.0000x reference)
//
#include <hip/hip_runtime.h>
#include <math.h>

// (B,C,H,W) = (64,512,28,28)
#define NC    512
#define CST   784          // H*W
#define SEG   64
#define NSEG  8
#define GSZ   25690112
#define NBLK  784          // 50176 columns / 64 lanes

__global__ __launch_bounds__(512, 4) void k_fused(const float* __restrict__ x,
                                                  const float* __restrict__ w,
                                                  float* __restrict__ g,
                                                  float* __restrict__ part) {
    const int lane = threadIdx.x & 63;
    const int s    = threadIdx.x >> 6;          // wave id = channel segment
    const int p    = blockIdx.x * 64 + lane;    // column id
    const int b    = p / CST;
    const int hw   = p - b * CST;
    const size_t base = (size_t)b * (NC * CST) + hw;
    const float* xp = x + base;
    float*       gp = g + base;
    const int k0 = s * SEG;

    __shared__ float wl[NC];        // w padded: wl[511] = 0
    __shared__ float sA[NSEG][64];
    __shared__ float sB[NSEG][64];
    __shared__ float lpart[NSEG];

    wl[threadIdx.x] = (threadIdx.x < NC - 1) ? w[threadIdx.x] : 0.f;

    // ---- load this thread's 65-channel x slice into registers ----
    float xr[SEG + 1];
    #pragma unroll
    for (int j = 0; j < SEG; ++j)
        xr[j] = xp[(size_t)(k0 + j) * CST];
    float xtop = 0.f;
    if (s < NSEG - 1) xtop = xp[(size_t)(k0 + SEG) * CST];   // wave-uniform guard
    xr[SEG] = xtop;

    __syncthreads();   // wl visible

    // ---- phase A: per-segment partial sums (pure register math) ----
    float a = 0.f, bs = 0.f;
    #pragma unroll
    for (int j = 0; j < SEG; ++j) {
        const float wk = wl[k0 + j];          // broadcast read
        a  = fmaf(xr[j],     wk, a);          // A[k] = x[k]  * w[k]
        bs = fmaf(xr[j + 1], wk, bs);         // B[k] = x[k+1]* w[k]
    }
    sA[s][lane] = a;
    sB[s][lane] = bs;
    __syncthreads();

    // ---- g[k0] = sum_{t<s} A_t + sum_{t>=s} B_t ----
    float r = 0.f;
    #pragma unroll
    for (int t = 0; t < NSEG; ++t)
        r += (t < s) ? sA[t][lane] : sB[t][lane];

    // ---- phase B: emit g + loss (no loads; nt stores keep x L3-resident) ----
    float ls = 0.f;
    #pragma unroll
    for (int j = 0; j < SEG; ++j) {
        __builtin_nontemporal_store(r, gp + (size_t)(k0 + j) * CST);
        const float d = r - xr[j];
        ls = fmaf(d, d, ls);
        r = fmaf(wl[k0 + j], xr[j] - xr[j + 1], r);   // g[k+1] = g[k] + w[k](x[k]-x[k+1])
    }

    // ---- loss: wave reduce -> block reduce -> one float per block ----
    #pragma unroll
    for (int off = 32; off; off >>= 1) ls += __shfl_down(ls, off, 64);
    if (lane == 0) lpart[s] = ls;
    __syncthreads();
    if (threadIdx.x == 0) {
        float t = 0.f;
        #pragma unroll
        for (int i = 0; i < NSEG; ++i) t += lpart[i];
        part[blockIdx.x] = t;
    }
}

__global__ __launch_bounds__(256) void k_final(const float* __restrict__ part,
                                               float* __restrict__ out) {
    double s = 0.0;
    for (int i = threadIdx.x; i < NBLK; i += 256) s += (double)part[i];
    #pragma unroll
    for (int off = 32; off; off >>= 1) s += __shfl_down(s, off, 64);
    __shared__ double sm[4];
    if ((threadIdx.x & 63) == 0) sm[threadIdx.x >> 6] = s;
    __syncthreads();
    if (threadIdx.x == 0)
        out[0] = (float)(sqrt(sm[0] + sm[1] + sm[2] + sm[3]) * 0.0025);
}

extern "C" void kernel_launch(void* const* d_in, const int* in_sizes, int n_in,
                              void* d_out, int out_size, void* d_ws, size_t ws_size,
                              hipStream_t stream) {
    const float* x = (const float*)d_in[0];
    const float* w = (const float*)d_in[1];
    float* g = (float*)d_out;
    float* part = (float*)d_ws;

    k_fused<<<dim3(NBLK), dim3(512), 0, stream>>>(x, w, g, part);
    k_final<<<1, 256, 0, stream>>>(part, g + GSZ);
}